// Round 9
// baseline (614.022 us; speedup 1.0000x reference)
//
#include <hip/hip_runtime.h>

#define NROWS 8192
#define DIM   512

typedef __attribute__((ext_vector_type(8))) short short8;
typedef __attribute__((ext_vector_type(4))) float f32x4;

__device__ inline unsigned short f2bf(float x) {
    unsigned u = __float_as_uint(x);
    u += 0x7fffu + ((u >> 16) & 1u);
    return (unsigned short)(u >> 16);
}
__device__ inline float bf2f(unsigned short h) {
    return __uint_as_float(((unsigned)h) << 16);
}

// ---------------------------------------------------------------------------
// Fast path kernel 0: split f32 -> (hi, lo) bf16 arrays for d1 and d2.
// ---------------------------------------------------------------------------
__global__ __launch_bounds__(256) void dm_split(const float* __restrict__ d1,
                                                const float* __restrict__ d2,
                                                unsigned short* __restrict__ Ahi,
                                                unsigned short* __restrict__ Alo,
                                                unsigned short* __restrict__ Bhi,
                                                unsigned short* __restrict__ Blo) {
    const long long t = (long long)blockIdx.x * 256 + threadIdx.x;
    const long long e = t * 8;
    const long long half = (long long)NROWS * DIM;
    const bool second = (e >= half);
    const float* src = second ? d2 : d1;
    unsigned short* hid = second ? Bhi : Ahi;
    unsigned short* lod = second ? Blo : Alo;
    const long long o = second ? e - half : e;
    float4 x0 = *(const float4*)(src + o);
    float4 x1 = *(const float4*)(src + o + 4);
    float xs[8] = {x0.x, x0.y, x0.z, x0.w, x1.x, x1.y, x1.z, x1.w};
    unsigned short hs[8], ls[8];
#pragma unroll
    for (int i = 0; i < 8; ++i) {
        hs[i] = f2bf(xs[i]);
        ls[i] = f2bf(xs[i] - bf2f(hs[i]));
    }
    *(short8*)(hid + o) = *(short8*)hs;
    *(short8*)(lod + o) = *(short8*)ls;
}

// ---------------------------------------------------------------------------
// Fast path kernel 1: f32 norms of d2 rows.
// ---------------------------------------------------------------------------
__global__ __launch_bounds__(256) void dm_norms2(const float* __restrict__ d2,
                                                 float* __restrict__ n2) {
    const int wave = threadIdx.x >> 6;
    const int lane = threadIdx.x & 63;
    const int r = blockIdx.x * 4 + wave;
    const float* src = d2 + (size_t)r * DIM;
    float4 a = *(const float4*)(src + lane * 4);
    float4 b = *(const float4*)(src + 256 + lane * 4);
    float s = a.x * a.x + a.y * a.y + a.z * a.z + a.w * a.w
            + b.x * b.x + b.y * b.y + b.z * b.z + b.w * b.w;
#pragma unroll
    for (int m = 32; m >= 1; m >>= 1) s += __shfl_xor(s, m);
    if (lane == 0) n2[r] = s;
}

// ---------------------------------------------------------------------------
// Fast path kernel 2 (v2): bf16-split MFMA distance GEMM + fused top-2.
// Same geometry as v1 (128x128 tile, 4 waves x (32 rows x 128 cols),
// frag-major conflict-free LDS, virtual K=1536) but restructured pipeline:
//   - B staged via global_load_lds (per-lane global addr -> linear LDS slot,
//     no VGPR round-trip)
//   - ring-3 LDS buffers, DMA issued 2 tile-steps ahead (~2 iters latency)
//   - ONE raw s_barrier per step + counted vmcnt(4) (never drain to 0)
//   - flat 192-step loop (pipeline flows across ct boundaries)
// Safety: DMA-issue sits AFTER the barrier and targets buf[(s+2)%3] =
// buf[(s-1)%3], whose reads completed before each wave's iter-(s-1) MFMAs
// (lgkmcnt-gated), which precede this barrier. vmcnt(4) before the barrier
// guarantees each wave's step-s DMAs and A(s) regs have landed.
// ---------------------------------------------------------------------------
#define NSPLIT 16
#define SLICE (NROWS / NSPLIT)   // 512
#define NCT   (SLICE / 128)      // 4
#define NKT   48
#define NSTEPS (NCT * NKT)       // 192

__device__ __forceinline__ void gload_lds16(const void* g, void* l) {
    __builtin_amdgcn_global_load_lds((const unsigned int*)g, (unsigned int*)l,
                                     16, 0, 0);
}

__global__ __launch_bounds__(256, 2) void dm_match_mfma(
        const unsigned short* __restrict__ Ahi, const unsigned short* __restrict__ Alo,
        const unsigned short* __restrict__ Bhi, const unsigned short* __restrict__ Blo,
        const float* __restrict__ n2, float4* __restrict__ part) {
    __shared__ short8 Bs[3][8][64];   // 24 KB ring, frag-major

    const int tid = threadIdx.x;
    const int l   = tid & 63;
    const int w   = tid >> 6;
    const int rb  = blockIdx.x >> 4;
    const int sp  = blockIdx.x & (NSPLIT - 1);
    const int row0 = rb * 128;
    const int col0 = sp * SLICE;
    const int lr = l & 15;    // row/col within fragment
    const int lk = l >> 4;    // k-octet

    const long long arow0 = (long long)(row0 + (2 * w + 0) * 16 + lr) * DIM + lk * 8;
    const long long arow1 = (long long)(row0 + (2 * w + 1) * 16 + lr) * DIM + lk * 8;
    const long long brow0 = (long long)((2 * w + 0) * 16 + lr) * DIM + lk * 8;
    const long long brow1 = (long long)((2 * w + 1) * 16 + lr) * DIM + lk * 8;

    // phase(kt): kt<16 Ahi.Bhi | kt<32 Ahi.Blo | kt<48 Alo.Bhi
    auto loadA = [&](int step, short8& a0, short8& a1) {
        const int kt = step % NKT;
        const unsigned short* A = (kt < 32) ? Ahi : Alo;
        const int k0 = (kt & 15) * 32;
        a0 = *(const short8*)(A + arow0 + k0);
        a1 = *(const short8*)(A + arow1 + k0);
    };
    auto issueDMA = [&](int step) {
        const int ct = step / NKT;
        const int kt = step % NKT;
        const unsigned short* B = (kt >= 16 && kt < 32) ? Blo : Bhi;
        const long long cb = (long long)(col0 + ct * 128) * DIM + (kt & 15) * 32;
        const int buf = step % 3;
        gload_lds16(B + cb + brow0, &Bs[buf][2 * w + 0][0]);
        gload_lds16(B + cb + brow1, &Bs[buf][2 * w + 1][0]);
    };

    float v0[8], v1[8];
    int   i0[8], i1[8];
#pragma unroll
    for (int s = 0; s < 8; ++s) { v0[s] = 3.0e38f; v1[s] = 3.0e38f; i0[s] = 0; i1[s] = 0; }

    f32x4 acc[2][8];
#pragma unroll
    for (int m = 0; m < 2; ++m)
#pragma unroll
        for (int n = 0; n < 8; ++n) acc[m][n] = (f32x4){0.f, 0.f, 0.f, 0.f};

    short8 cA0, cA1, nA0, nA1;
    loadA(0, cA0, cA1);
    issueDMA(0);
    issueDMA(1);

    for (int s = 0; s < NSTEPS; ++s) {
        // A prefetch for s+1 (clamped; last-iter redundant load is harmless)
        loadA((s + 1 < NSTEPS) ? s + 1 : s, nA0, nA1);
        // wait: my step-s DMAs + A(s) landed (keep 4 newest: DMA(s+1)+A(s+1))
        asm volatile("s_waitcnt vmcnt(4)" ::: "memory");
        __builtin_amdgcn_s_barrier();          // all waves' step-s DMAs landed
        __builtin_amdgcn_sched_barrier(0);     // pin ds_reads below barrier

        const int buf = s % 3;
        short8 b0 = Bs[buf][0][l], b1 = Bs[buf][1][l];
        short8 b2 = Bs[buf][2][l], b3 = Bs[buf][3][l];
        short8 b4 = Bs[buf][4][l], b5 = Bs[buf][5][l];
        short8 b6 = Bs[buf][6][l], b7 = Bs[buf][7][l];

        if (s + 2 < NSTEPS) issueDMA(s + 2);   // safe: buf[(s+2)%3]=buf[(s-1)%3]

        acc[0][0] = __builtin_amdgcn_mfma_f32_16x16x32_bf16(cA0, b0, acc[0][0], 0, 0, 0);
        acc[0][1] = __builtin_amdgcn_mfma_f32_16x16x32_bf16(cA0, b1, acc[0][1], 0, 0, 0);
        acc[0][2] = __builtin_amdgcn_mfma_f32_16x16x32_bf16(cA0, b2, acc[0][2], 0, 0, 0);
        acc[0][3] = __builtin_amdgcn_mfma_f32_16x16x32_bf16(cA0, b3, acc[0][3], 0, 0, 0);
        acc[0][4] = __builtin_amdgcn_mfma_f32_16x16x32_bf16(cA0, b4, acc[0][4], 0, 0, 0);
        acc[0][5] = __builtin_amdgcn_mfma_f32_16x16x32_bf16(cA0, b5, acc[0][5], 0, 0, 0);
        acc[0][6] = __builtin_amdgcn_mfma_f32_16x16x32_bf16(cA0, b6, acc[0][6], 0, 0, 0);
        acc[0][7] = __builtin_amdgcn_mfma_f32_16x16x32_bf16(cA0, b7, acc[0][7], 0, 0, 0);
        acc[1][0] = __builtin_amdgcn_mfma_f32_16x16x32_bf16(cA1, b0, acc[1][0], 0, 0, 0);
        acc[1][1] = __builtin_amdgcn_mfma_f32_16x16x32_bf16(cA1, b1, acc[1][1], 0, 0, 0);
        acc[1][2] = __builtin_amdgcn_mfma_f32_16x16x32_bf16(cA1, b2, acc[1][2], 0, 0, 0);
        acc[1][3] = __builtin_amdgcn_mfma_f32_16x16x32_bf16(cA1, b3, acc[1][3], 0, 0, 0);
        acc[1][4] = __builtin_amdgcn_mfma_f32_16x16x32_bf16(cA1, b4, acc[1][4], 0, 0, 0);
        acc[1][5] = __builtin_amdgcn_mfma_f32_16x16x32_bf16(cA1, b5, acc[1][5], 0, 0, 0);
        acc[1][6] = __builtin_amdgcn_mfma_f32_16x16x32_bf16(cA1, b6, acc[1][6], 0, 0, 0);
        acc[1][7] = __builtin_amdgcn_mfma_f32_16x16x32_bf16(cA1, b7, acc[1][7], 0, 0, 0);

        cA0 = nA0; cA1 = nA1;

        if (s % NKT == NKT - 1) {
            // ct finished: fused selection on s = n2[c] - 2*dot, reset acc.
            // C/D layout (m89): col = lane&15, row = (lane>>4)*4 + reg.
            const int colblk = col0 + (s / NKT) * 128;
#pragma unroll
            for (int n = 0; n < 8; ++n) {
                const int c = colblk + n * 16 + lr;
                const float nv = n2[c];
#pragma unroll
                for (int m = 0; m < 2; ++m) {
#pragma unroll
                    for (int r = 0; r < 4; ++r) {
                        const float sv = fmaf(-2.f, acc[m][n][r], nv);
                        const int slot = m * 4 + r;
                        if (sv < v1[slot]) {
                            if (sv < v0[slot]) { v1[slot] = v0[slot]; i1[slot] = i0[slot];
                                                 v0[slot] = sv;       i0[slot] = c; }
                            else               { v1[slot] = sv;       i1[slot] = c; }
                        }
                    }
                }
            }
#pragma unroll
            for (int m = 0; m < 2; ++m)
#pragma unroll
                for (int n = 0; n < 8; ++n) acc[m][n] = (f32x4){0.f, 0.f, 0.f, 0.f};
        }
    }

    // merge top-2 across the 16 col-lanes of each row (lex (value, idx)).
#pragma unroll
    for (int slot = 0; slot < 8; ++slot) {
        float a0 = v0[slot], a1 = v1[slot];
        int   ai0 = i0[slot], ai1 = i1[slot];
#pragma unroll
        for (int m = 1; m <= 8; m <<= 1) {
            float b0 = __shfl_xor(a0, m);
            float b1 = __shfl_xor(a1, m);
            int   bi0 = __shfl_xor(ai0, m);
            int   bi1 = __shfl_xor(ai1, m);
            if (b0 < a0 || (b0 == a0 && bi0 < ai0)) {
                if (a0 < b1 || (a0 == b1 && ai0 < bi1)) { a1 = a0; ai1 = ai0; }
                else                                    { a1 = b1; ai1 = bi1; }
                a0 = b0; ai0 = bi0;
            } else if (b0 < a1 || (b0 == a1 && bi0 < ai1)) {
                a1 = b0; ai1 = bi0;
            }
        }
        if (lr == 0) {
            const int row = row0 + w * 32 + (slot >> 2) * 16 + lk * 4 + (slot & 3);
            float4 p;
            p.x = a0; p.y = a1;
            p.z = __int_as_float(ai0); p.w = __int_as_float(ai1);
            part[row * NSPLIT + sp] = p;
        }
    }
}

// ---------------------------------------------------------------------------
// Fast path kernel 3: exact f64 rescore of the 32 candidates/row.
// ---------------------------------------------------------------------------
#define NCAND 32
__global__ __launch_bounds__(256) void dm_rescore(const float* __restrict__ d1,
                                                  const float* __restrict__ d2,
                                                  const float4* __restrict__ part,
                                                  float* __restrict__ out) {
    __shared__ double cv[NCAND];
    __shared__ int    cj[NCAND];
    const int row = blockIdx.x;
    const int c = threadIdx.x >> 3;   // candidate 0..31
    const int p = threadIdx.x & 7;    // 64 dims each
    float4 P = part[row * NSPLIT + (c >> 1)];
    const int j = __float_as_int((c & 1) ? P.w : P.z);

    const float* a = d1 + (size_t)row * DIM + p * 64;
    const float* b = d2 + (size_t)j   * DIM + p * 64;
    double s = 0.0;
#pragma unroll
    for (int q = 0; q < 64; q += 4) {
        float4 x = *(const float4*)(a + q);
        float4 y = *(const float4*)(b + q);
        double e;
        e = (double)x.x - (double)y.x; s = fma(e, e, s);
        e = (double)x.y - (double)y.y; s = fma(e, e, s);
        e = (double)x.z - (double)y.z; s = fma(e, e, s);
        e = (double)x.w - (double)y.w; s = fma(e, e, s);
    }
    s += __shfl_xor(s, 1);
    s += __shfl_xor(s, 2);
    s += __shfl_xor(s, 4);
    if (p == 0) { cv[c] = s; cj[c] = j; }
    __syncthreads();
    if (threadIdx.x == 0) {
        double b0 = 1.0e300, b1 = 1.0e300;
        int    j0 = 0, j1 = 0;
        for (int q = 0; q < NCAND; ++q) {
            const double v = cv[q];
            const int   jj = cj[q];
            if (v < b0 || (v == b0 && jj < j0)) { b1 = b0; j1 = j0; b0 = v; j0 = jj; }
            else if (v < b1 || (v == b1 && jj < j1)) { b1 = v; j1 = jj; }
        }
        const double d0  = sqrt(b0);
        const double d1v = sqrt(b1);
        const double dr  = d0 / d1v;
        const bool mask = (dr <= 0.8);
        out[row] = mask ? (float)dr : 0.f;
        out[NROWS + 2 * row]     = (float)row;
        out[NROWS + 2 * row + 1] = (float)j0;
        out[3 * NROWS + row] = mask ? 1.f : 0.f;
    }
}

// ===========================================================================
// Fallback path (round-4 proven kernels) if ws_size is too small.
// ===========================================================================
__global__ __launch_bounds__(256) void dmfb_norms(const float* __restrict__ d1,
                                                  const float* __restrict__ d2,
                                                  double* __restrict__ n1,
                                                  double* __restrict__ n2) {
    const int wave = threadIdx.x >> 6;
    const int lane = threadIdx.x & 63;
    const int r = blockIdx.x * 4 + wave;
    const float* src = (r < NROWS) ? (d1 + (size_t)r * DIM)
                                   : (d2 + (size_t)(r - NROWS) * DIM);
    float4 a = *(const float4*)(src + lane * 4);
    float4 b = *(const float4*)(src + 256 + lane * 4);
    double s = (double)a.x * a.x + (double)a.y * a.y
             + (double)a.z * a.z + (double)a.w * a.w
             + (double)b.x * b.x + (double)b.y * b.y
             + (double)b.z * b.z + (double)b.w * b.w;
#pragma unroll
    for (int m = 32; m >= 1; m >>= 1) s += __shfl_xor(s, m);
    if (lane == 0) {
        if (r < NROWS) n1[r] = s;
        else           n2[r - NROWS] = s;
    }
}

__global__ __launch_bounds__(256) void dmfb_match(const float* __restrict__ d1,
                                                  const float* __restrict__ d2,
                                                  const double* __restrict__ n2,
                                                  double* __restrict__ pv0,
                                                  double* __restrict__ pv1,
                                                  int* __restrict__ pi0) {
    __shared__ float As[32][64];
    __shared__ float Bsh[32][64];
    const int rb   = blockIdx.x / 4;
    const int sp   = blockIdx.x % 4;
    const int row0 = rb * 64;
    const int col0 = sp * 2048;
    const int tid = threadIdx.x;
    const int tx  = tid & 15;
    const int ty  = tid >> 4;
    const int sc  = tid >> 3;
    const int sk  = (tid & 7) << 2;
    double v0[4], v1[4];
    int    i0[4];
#pragma unroll
    for (int r = 0; r < 4; ++r) { v0[r] = 1.0e300; v1[r] = 1.0e300; i0[r] = 0; }
    for (int ct = 0; ct < 32; ++ct) {
        const int c0 = col0 + ct * 64;
        double acc64[4][4];
#pragma unroll
        for (int r = 0; r < 4; ++r)
#pragma unroll
            for (int c = 0; c < 4; ++c) acc64[r][c] = 0.0;
        for (int kk = 0; kk < DIM; kk += 32) {
            float4 a0 = *(const float4*)(d1 + (size_t)(row0 + sc)      * DIM + kk + sk);
            float4 a1 = *(const float4*)(d1 + (size_t)(row0 + sc + 32) * DIM + kk + sk);
            float4 b0 = *(const float4*)(d2 + (size_t)(c0  + sc)      * DIM + kk + sk);
            float4 b1 = *(const float4*)(d2 + (size_t)(c0  + sc + 32) * DIM + kk + sk);
            __syncthreads();
            {
                const int wc0 = sc ^ sk;
                const int wc1 = (sc + 32) ^ sk;
                As[sk + 0][wc0] = a0.x; As[sk + 1][wc0] = a0.y;
                As[sk + 2][wc0] = a0.z; As[sk + 3][wc0] = a0.w;
                As[sk + 0][wc1] = a1.x; As[sk + 1][wc1] = a1.y;
                As[sk + 2][wc1] = a1.z; As[sk + 3][wc1] = a1.w;
                Bsh[sk + 0][wc0] = b0.x; Bsh[sk + 1][wc0] = b0.y;
                Bsh[sk + 2][wc0] = b0.z; Bsh[sk + 3][wc0] = b0.w;
                Bsh[sk + 0][wc1] = b1.x; Bsh[sk + 1][wc1] = b1.y;
                Bsh[sk + 2][wc1] = b1.z; Bsh[sk + 3][wc1] = b1.w;
            }
            __syncthreads();
            float acc[4][4];
#pragma unroll
            for (int r = 0; r < 4; ++r)
#pragma unroll
                for (int c = 0; c < 4; ++c) acc[r][c] = 0.f;
#pragma unroll
            for (int k = 0; k < 32; ++k) {
                const int rsw = (k >> 2) << 2;
                float4 a = *(const float4*)&As[k][(ty * 4) ^ rsw];
                float4 b = *(const float4*)&Bsh[k][(tx * 4) ^ rsw];
                acc[0][0] = fmaf(a.x, b.x, acc[0][0]);
                acc[0][1] = fmaf(a.x, b.y, acc[0][1]);
                acc[0][2] = fmaf(a.x, b.z, acc[0][2]);
                acc[0][3] = fmaf(a.x, b.w, acc[0][3]);
                acc[1][0] = fmaf(a.y, b.x, acc[1][0]);
                acc[1][1] = fmaf(a.y, b.y, acc[1][1]);
                acc[1][2] = fmaf(a.y, b.z, acc[1][2]);
                acc[1][3] = fmaf(a.y, b.w, acc[1][3]);
                acc[2][0] = fmaf(a.z, b.x, acc[2][0]);
                acc[2][1] = fmaf(a.z, b.y, acc[2][1]);
                acc[2][2] = fmaf(a.z, b.z, acc[2][2]);
                acc[2][3] = fmaf(a.z, b.w, acc[2][3]);
                acc[3][0] = fmaf(a.w, b.x, acc[3][0]);
                acc[3][1] = fmaf(a.w, b.y, acc[3][1]);
                acc[3][2] = fmaf(a.w, b.z, acc[3][2]);
                acc[3][3] = fmaf(a.w, b.w, acc[3][3]);
            }
#pragma unroll
            for (int r = 0; r < 4; ++r)
#pragma unroll
                for (int c = 0; c < 4; ++c) acc64[r][c] += (double)acc[r][c];
        }
        const int cbase = c0 + tx * 4;
        double nna[4];
#pragma unroll
        for (int c = 0; c < 4; ++c) nna[c] = n2[cbase + c];
#pragma unroll
        for (int r = 0; r < 4; ++r) {
#pragma unroll
            for (int c = 0; c < 4; ++c) {
                const double s = nna[c] - 2.0 * acc64[r][c];
                const int j = cbase + c;
                if (s < v0[r]) { v1[r] = v0[r]; v0[r] = s; i0[r] = j; }
                else if (s < v1[r]) { v1[r] = s; }
            }
        }
    }
#pragma unroll
    for (int r = 0; r < 4; ++r) {
        double a0 = v0[r], a1 = v1[r];
        int    ai = i0[r];
#pragma unroll
        for (int m = 1; m <= 8; m <<= 1) {
            double b0 = __shfl_xor(a0, m);
            double b1 = __shfl_xor(a1, m);
            int    bi = __shfl_xor(ai, m);
            bool take = (b0 < a0) || (b0 == a0 && bi < ai);
            if (take) { a1 = fmin(a0, b1); a0 = b0; ai = bi; }
            else      { a1 = fmin(a1, b0); }
        }
        if (tx == 0) {
            const int row = row0 + ty * 4 + r;
            pv0[sp * NROWS + row] = a0;
            pv1[sp * NROWS + row] = a1;
            pi0[sp * NROWS + row] = ai;
        }
    }
}

__global__ __launch_bounds__(256) void dmfb_finalize(const double* __restrict__ n1,
                                                     const double* __restrict__ pv0,
                                                     const double* __restrict__ pv1,
                                                     const int* __restrict__ pi0,
                                                     float* __restrict__ out) {
    const int i = blockIdx.x * blockDim.x + threadIdx.x;
    if (i >= NROWS) return;
    double a0 = pv0[i], a1 = pv1[i];
    int    ai = pi0[i];
#pragma unroll
    for (int h = 1; h < 4; ++h) {
        const double b0 = pv0[h * NROWS + i];
        const double b1 = pv1[h * NROWS + i];
        const int    bi = pi0[h * NROWS + i];
        bool take = (b0 < a0) || (b0 == a0 && bi < ai);
        if (take) { a1 = fmin(a0, b1); a0 = b0; ai = bi; }
        else      { a1 = fmin(a1, b0); }
    }
    const double nn = n1[i];
    const double d0  = sqrt(fmax(nn + a0, 0.0));
    const double d1v = sqrt(fmax(nn + a1, 0.0));
    const float ratio = (float)(d0 / d1v);
    const bool mask = (ratio <= 0.8f);
    out[i] = mask ? ratio : 0.f;
    out[NROWS + 2 * i]     = (float)i;
    out[NROWS + 2 * i + 1] = (float)ai;
    out[3 * NROWS + i] = mask ? 1.f : 0.f;
}

extern "C" void kernel_launch(void* const* d_in, const int* in_sizes, int n_in,
                              void* d_out, int out_size, void* d_ws, size_t ws_size,
                              hipStream_t stream) {
    const float* d1 = (const float*)d_in[0];
    const float* d2 = (const float*)d_in[1];
    float* out = (float*)d_out;

    const size_t ELEMS = (size_t)NROWS * DIM;              // 4,194,304
    const size_t need = 4 * ELEMS * 2 + NROWS * 4          // hi/lo arrays + n2
                      + (size_t)NROWS * NSPLIT * 16;       // partials
    if (ws_size >= need) {
        unsigned short* Ahi = (unsigned short*)d_ws;
        unsigned short* Alo = Ahi + ELEMS;
        unsigned short* Bhi = Alo + ELEMS;
        unsigned short* Blo = Bhi + ELEMS;
        float* n2 = (float*)(Blo + ELEMS);
        float4* part = (float4*)(n2 + NROWS);

        dm_split<<<(2 * ELEMS) / (256 * 8), 256, 0, stream>>>(d1, d2, Ahi, Alo, Bhi, Blo);
        dm_norms2<<<NROWS / 4, 256, 0, stream>>>(d2, n2);
        dm_match_mfma<<<(NROWS / 128) * NSPLIT, 256, 0, stream>>>(Ahi, Alo, Bhi, Blo, n2, part);
        dm_rescore<<<NROWS, 256, 0, stream>>>(d1, d2, part, out);
    } else {
        double* n1  = (double*)d_ws;
        double* n2  = n1 + NROWS;
        double* pv0 = n2 + NROWS;
        double* pv1 = pv0 + 4 * NROWS;
        int*    pi0 = (int*)(pv1 + 4 * NROWS);
        dmfb_norms<<<(2 * NROWS) / 4, 256, 0, stream>>>(d1, d2, n1, n2);
        dmfb_match<<<(NROWS / 64) * 4, 256, 0, stream>>>(d1, d2, n2, pv0, pv1, pi0);
        dmfb_finalize<<<NROWS / 256, 256, 0, stream>>>(n1, pv0, pv1, pi0, out);
    }
}

// Round 11
// 510.359 us; speedup vs baseline: 1.2031x; 1.2031x over previous
//
#include <hip/hip_runtime.h>

#define NROWS 8192
#define DIM   512

typedef __attribute__((ext_vector_type(8))) short short8;
typedef __attribute__((ext_vector_type(4))) float f32x4;

__device__ inline unsigned short f2bf(float x) {
    unsigned u = __float_as_uint(x);
    u += 0x7fffu + ((u >> 16) & 1u);
    return (unsigned short)(u >> 16);
}
__device__ inline float bf2f(unsigned short h) {
    return __uint_as_float(((unsigned)h) << 16);
}

// ---------------------------------------------------------------------------
// Fast path kernel 0: split f32 -> (hi, lo) bf16 arrays for d1 and d2.
// ---------------------------------------------------------------------------
__global__ __launch_bounds__(256) void dm_split(const float* __restrict__ d1,
                                                const float* __restrict__ d2,
                                                unsigned short* __restrict__ Ahi,
                                                unsigned short* __restrict__ Alo,
                                                unsigned short* __restrict__ Bhi,
                                                unsigned short* __restrict__ Blo) {
    const long long t = (long long)blockIdx.x * 256 + threadIdx.x;
    const long long e = t * 8;
    const long long half = (long long)NROWS * DIM;
    const bool second = (e >= half);
    const float* src = second ? d2 : d1;
    unsigned short* hid = second ? Bhi : Ahi;
    unsigned short* lod = second ? Blo : Alo;
    const long long o = second ? e - half : e;
    float4 x0 = *(const float4*)(src + o);
    float4 x1 = *(const float4*)(src + o + 4);
    float xs[8] = {x0.x, x0.y, x0.z, x0.w, x1.x, x1.y, x1.z, x1.w};
    unsigned short hs[8], ls[8];
#pragma unroll
    for (int i = 0; i < 8; ++i) {
        hs[i] = f2bf(xs[i]);
        ls[i] = f2bf(xs[i] - bf2f(hs[i]));
    }
    *(short8*)(hid + o) = *(short8*)hs;
    *(short8*)(lod + o) = *(short8*)ls;
}

// ---------------------------------------------------------------------------
// Fast path kernel 1: f32 norms of d2 rows.
// ---------------------------------------------------------------------------
__global__ __launch_bounds__(256) void dm_norms2(const float* __restrict__ d2,
                                                 float* __restrict__ n2) {
    const int wave = threadIdx.x >> 6;
    const int lane = threadIdx.x & 63;
    const int r = blockIdx.x * 4 + wave;
    const float* src = d2 + (size_t)r * DIM;
    float4 a = *(const float4*)(src + lane * 4);
    float4 b = *(const float4*)(src + 256 + lane * 4);
    float s = a.x * a.x + a.y * a.y + a.z * a.z + a.w * a.w
            + b.x * b.x + b.y * b.y + b.z * b.z + b.w * b.w;
#pragma unroll
    for (int m = 32; m >= 1; m >>= 1) s += __shfl_xor(s, m);
    if (lane == 0) n2[r] = s;
}

// ---------------------------------------------------------------------------
// Fast path kernel 2 (v3): bf16-split MFMA distance GEMM + fused top-2.
// Round-8 (444us) structure, but tile 256x128: wave owns 64 rows = 4 m-frags
// x 8 n-frags = 32 MFMA per K-step (2x MFMA per barrier vs v1), same 8
// ds_read_b128 + 2-barrier staging. Grid 512 blocks = exactly 2/CU.
// Selection: per-ct per-thread top2 over 8 cols -> lr-butterfly (all 16
// lanes converge) -> merged into a running top-2 DISTRIBUTED one slot per
// lr-lane (slot = m*4+r), so persistent state is 4 regs/thread and each
// lane finally owns one row's slice-top-2. No final merge needed.
// ---------------------------------------------------------------------------
#define NSPLIT 16
#define SLICE (NROWS / NSPLIT)   // 512
#define NCT   (SLICE / 128)      // 4
#define NKT   48

__global__ __launch_bounds__(256, 2) void dm_match_mfma(
        const unsigned short* __restrict__ Ahi, const unsigned short* __restrict__ Alo,
        const unsigned short* __restrict__ Bhi, const unsigned short* __restrict__ Blo,
        const float* __restrict__ n2, float4* __restrict__ part) {
    __shared__ short8 Bs[8][64];   // 8 KB, frag-major

    const int tid = threadIdx.x;
    const int l   = tid & 63;
    const int w   = tid >> 6;
    const int rb  = blockIdx.x >> 4;       // 32 row-blocks of 256
    const int sp  = blockIdx.x & (NSPLIT - 1);
    const int row0 = rb * 256;
    const int col0 = sp * SLICE;
    const int lr = l & 15;    // col within fragment / staging col group
    const int lk = l >> 4;    // k-octet

    // A: 4 m-frags per wave (rows row0 + w*64 + m*16 + lr)
    long long arow[4];
#pragma unroll
    for (int m = 0; m < 4; ++m)
        arow[m] = (long long)(row0 + w * 64 + m * 16 + lr) * DIM + lk * 8;
    // B staging rows (cols) for this wave: frags 2w, 2w+1
    const long long brow0 = (long long)((2 * w + 0) * 16 + lr) * DIM + lk * 8;
    const long long brow1 = (long long)((2 * w + 1) * 16 + lr) * DIM + lk * 8;

    // running top-2 for the slot this lane owns (slot = lr = m*4+r):
    // row = row0 + w*64 + (lr>>2)*16 + lk*4 + (lr&3)
    float rv0 = 3.0e38f, rv1 = 3.0e38f;
    int   ri0 = 0, ri1 = 0;

    for (int ct = 0; ct < NCT; ++ct) {
        const int colblk = col0 + ct * 128;
        const long long bbase = (long long)colblk * DIM;

        f32x4 acc[4][8];
#pragma unroll
        for (int m = 0; m < 4; ++m)
#pragma unroll
            for (int n = 0; n < 8; ++n) acc[m][n] = (f32x4){0.f, 0.f, 0.f, 0.f};

        // prefetch kt = 0 (Ahi, Bhi, k0 = 0)
        short8 ga[4], na[4];
#pragma unroll
        for (int m = 0; m < 4; ++m) ga[m] = *(const short8*)(Ahi + arow[m]);
        short8 gb0 = *(const short8*)(Bhi + bbase + brow0);
        short8 gb1 = *(const short8*)(Bhi + bbase + brow1);

        for (int kt = 0; kt < NKT; ++kt) {
            // prefetch kt+1 (clamped; last-iter redundant load is harmless)
            const int kn = (kt + 1 < NKT) ? kt + 1 : kt;
            const unsigned short* An = (kn < 32) ? Ahi : Alo;
            const unsigned short* Bn = (kn >= 16 && kn < 32) ? Blo : Bhi;
            const int k0n = (kn & 15) * 32;
#pragma unroll
            for (int m = 0; m < 4; ++m) na[m] = *(const short8*)(An + arow[m] + k0n);
            short8 nb0 = *(const short8*)(Bn + bbase + brow0 + k0n);
            short8 nb1 = *(const short8*)(Bn + bbase + brow1 + k0n);

            __syncthreads();           // previous B tile fully consumed
            Bs[2 * w + 0][l] = gb0;    // lane-linear 16B: conflict-free
            Bs[2 * w + 1][l] = gb1;
            __syncthreads();

            short8 b0 = Bs[0][l], b1 = Bs[1][l], b2 = Bs[2][l], b3 = Bs[3][l];
            short8 b4 = Bs[4][l], b5 = Bs[5][l], b6 = Bs[6][l], b7 = Bs[7][l];

#pragma unroll
            for (int m = 0; m < 4; ++m) {
                acc[m][0] = __builtin_amdgcn_mfma_f32_16x16x32_bf16(ga[m], b0, acc[m][0], 0, 0, 0);
                acc[m][1] = __builtin_amdgcn_mfma_f32_16x16x32_bf16(ga[m], b1, acc[m][1], 0, 0, 0);
                acc[m][2] = __builtin_amdgcn_mfma_f32_16x16x32_bf16(ga[m], b2, acc[m][2], 0, 0, 0);
                acc[m][3] = __builtin_amdgcn_mfma_f32_16x16x32_bf16(ga[m], b3, acc[m][3], 0, 0, 0);
                acc[m][4] = __builtin_amdgcn_mfma_f32_16x16x32_bf16(ga[m], b4, acc[m][4], 0, 0, 0);
                acc[m][5] = __builtin_amdgcn_mfma_f32_16x16x32_bf16(ga[m], b5, acc[m][5], 0, 0, 0);
                acc[m][6] = __builtin_amdgcn_mfma_f32_16x16x32_bf16(ga[m], b6, acc[m][6], 0, 0, 0);
                acc[m][7] = __builtin_amdgcn_mfma_f32_16x16x32_bf16(ga[m], b7, acc[m][7], 0, 0, 0);
            }
#pragma unroll
            for (int m = 0; m < 4; ++m) ga[m] = na[m];
            gb0 = nb0; gb1 = nb1;
        }

        // ---- per-ct fused selection on s = n2[c] - 2*dot ----
        // C/D layout (m89): col = lane&15 (d2 idx), row = (lane>>4)*4 + reg.
        float n2v[8];
#pragma unroll
        for (int n = 0; n < 8; ++n) n2v[n] = n2[colblk + n * 16 + lr];

#pragma unroll
        for (int m = 0; m < 4; ++m) {
#pragma unroll
            for (int r = 0; r < 4; ++r) {
                // per-thread top2 over the 8 n-frags (columns ascend with n)
                float a0 = 3.0e38f, a1 = 3.0e38f;
                int   ai0 = 0, ai1 = 0;
#pragma unroll
                for (int n = 0; n < 8; ++n) {
                    const float sv = fmaf(-2.f, acc[m][n][r], n2v[n]);
                    const int c = colblk + n * 16 + lr;
                    if (sv < a1) {
                        if (sv < a0) { a1 = a0; ai1 = ai0; a0 = sv; ai0 = c; }
                        else         { a1 = sv; ai1 = c; }
                    }
                }
                // butterfly across the 16 lr lanes (masks flip lr bits only;
                // lk preserved -> only same-row lanes merge). All lanes
                // converge to identical merged top-2 (lex (value,idx)).
#pragma unroll
                for (int msk = 1; msk <= 8; msk <<= 1) {
                    float b0 = __shfl_xor(a0, msk);
                    float b1 = __shfl_xor(a1, msk);
                    int   bi0 = __shfl_xor(ai0, msk);
                    int   bi1 = __shfl_xor(ai1, msk);
                    if (b0 < a0 || (b0 == a0 && bi0 < ai0)) {
                        if (a0 < b1 || (a0 == b1 && ai0 < bi1)) { a1 = a0; ai1 = ai0; }
                        else                                    { a1 = b1; ai1 = bi1; }
                        a0 = b0; ai0 = bi0;
                    } else if (b0 < a1 || (b0 == a1 && bi0 < ai1)) {
                        a1 = b0; ai1 = bi0;
                    }
                }
                // merge into the running state of the owning lane.
                // running indices are from earlier cts (strictly lower), so
                // ties resolve to the running entry.
                const bool mine = (lr == (m * 4 + r));
                const bool cfirst = (a0 < rv0);
                float n0 = cfirst ? a0 : rv0;
                int   ni0 = cfirst ? ai0 : ri0;
                float n1; int ni1;
                if (cfirst) { const bool rs = (rv0 <= a1); n1 = rs ? rv0 : a1; ni1 = rs ? ri0 : ai1; }
                else        { const bool rs = (rv1 <= a0); n1 = rs ? rv1 : a0; ni1 = rs ? ri1 : ai0; }
                if (mine) { rv0 = n0; ri0 = ni0; rv1 = n1; ri1 = ni1; }
            }
        }
    }

    // each lane owns one row's slice-top-2: write it.
    {
        const int row = row0 + w * 64 + (lr >> 2) * 16 + lk * 4 + (lr & 3);
        float4 p;
        p.x = rv0; p.y = rv1;
        p.z = __int_as_float(ri0); p.w = __int_as_float(ri1);
        part[row * NSPLIT + sp] = p;
    }
}

// ---------------------------------------------------------------------------
// Fast path kernel 3: exact f64 rescore of the 32 candidates/row.
// Output (floats): [0,8192) ratio-or-0, [8192,24576) idx pairs,
// [24576,32768) mask.
// ---------------------------------------------------------------------------
#define NCAND 32
__global__ __launch_bounds__(256) void dm_rescore(const float* __restrict__ d1,
                                                  const float* __restrict__ d2,
                                                  const float4* __restrict__ part,
                                                  float* __restrict__ out) {
    __shared__ double cv[NCAND];
    __shared__ int    cj[NCAND];
    const int row = blockIdx.x;
    const int c = threadIdx.x >> 3;   // candidate 0..31
    const int p = threadIdx.x & 7;    // 64 dims each
    float4 P = part[row * NSPLIT + (c >> 1)];
    const int j = __float_as_int((c & 1) ? P.w : P.z);

    const float* a = d1 + (size_t)row * DIM + p * 64;
    const float* b = d2 + (size_t)j   * DIM + p * 64;
    double s = 0.0;
#pragma unroll
    for (int q = 0; q < 64; q += 4) {
        float4 x = *(const float4*)(a + q);
        float4 y = *(const float4*)(b + q);
        double e;
        e = (double)x.x - (double)y.x; s = fma(e, e, s);
        e = (double)x.y - (double)y.y; s = fma(e, e, s);
        e = (double)x.z - (double)y.z; s = fma(e, e, s);
        e = (double)x.w - (double)y.w; s = fma(e, e, s);
    }
    s += __shfl_xor(s, 1);
    s += __shfl_xor(s, 2);
    s += __shfl_xor(s, 4);
    if (p == 0) { cv[c] = s; cj[c] = j; }
    __syncthreads();
    if (threadIdx.x == 0) {
        double b0 = 1.0e300, b1 = 1.0e300;
        int    j0 = 0, j1 = 0;
        for (int q = 0; q < NCAND; ++q) {
            const double v = cv[q];
            const int   jj = cj[q];
            if (v < b0 || (v == b0 && jj < j0)) { b1 = b0; j1 = j0; b0 = v; j0 = jj; }
            else if (v < b1 || (v == b1 && jj < j1)) { b1 = v; j1 = jj; }
        }
        const double d0  = sqrt(b0);
        const double d1v = sqrt(b1);
        const double dr  = d0 / d1v;
        const bool mask = (dr <= 0.8);
        out[row] = mask ? (float)dr : 0.f;
        out[NROWS + 2 * row]     = (float)row;
        out[NROWS + 2 * row + 1] = (float)j0;
        out[3 * NROWS + row] = mask ? 1.f : 0.f;
    }
}

// ===========================================================================
// Fallback path (round-4 proven kernels) if ws_size is too small.
// ===========================================================================
__global__ __launch_bounds__(256) void dmfb_norms(const float* __restrict__ d1,
                                                  const float* __restrict__ d2,
                                                  double* __restrict__ n1,
                                                  double* __restrict__ n2) {
    const int wave = threadIdx.x >> 6;
    const int lane = threadIdx.x & 63;
    const int r = blockIdx.x * 4 + wave;
    const float* src = (r < NROWS) ? (d1 + (size_t)r * DIM)
                                   : (d2 + (size_t)(r - NROWS) * DIM);
    float4 a = *(const float4*)(src + lane * 4);
    float4 b = *(const float4*)(src + 256 + lane * 4);
    double s = (double)a.x * a.x + (double)a.y * a.y
             + (double)a.z * a.z + (double)a.w * a.w
             + (double)b.x * b.x + (double)b.y * b.y
             + (double)b.z * b.z + (double)b.w * b.w;
#pragma unroll
    for (int m = 32; m >= 1; m >>= 1) s += __shfl_xor(s, m);
    if (lane == 0) {
        if (r < NROWS) n1[r] = s;
        else           n2[r - NROWS] = s;
    }
}

__global__ __launch_bounds__(256) void dmfb_match(const float* __restrict__ d1,
                                                  const float* __restrict__ d2,
                                                  const double* __restrict__ n2,
                                                  double* __restrict__ pv0,
                                                  double* __restrict__ pv1,
                                                  int* __restrict__ pi0) {
    __shared__ float As[32][64];
    __shared__ float Bsh[32][64];
    const int rb   = blockIdx.x / 4;
    const int sp   = blockIdx.x % 4;
    const int row0 = rb * 64;
    const int col0 = sp * 2048;
    const int tid = threadIdx.x;
    const int tx  = tid & 15;
    const int ty  = tid >> 4;
    const int sc  = tid >> 3;
    const int sk  = (tid & 7) << 2;
    double v0[4], v1[4];
    int    i0[4];
#pragma unroll
    for (int r = 0; r < 4; ++r) { v0[r] = 1.0e300; v1[r] = 1.0e300; i0[r] = 0; }
    for (int ct = 0; ct < 32; ++ct) {
        const int c0 = col0 + ct * 64;
        double acc64[4][4];
#pragma unroll
        for (int r = 0; r < 4; ++r)
#pragma unroll
            for (int c = 0; c < 4; ++c) acc64[r][c] = 0.0;
        for (int kk = 0; kk < DIM; kk += 32) {
            float4 a0 = *(const float4*)(d1 + (size_t)(row0 + sc)      * DIM + kk + sk);
            float4 a1 = *(const float4*)(d1 + (size_t)(row0 + sc + 32) * DIM + kk + sk);
            float4 b0 = *(const float4*)(d2 + (size_t)(c0  + sc)      * DIM + kk + sk);
            float4 b1 = *(const float4*)(d2 + (size_t)(c0  + sc + 32) * DIM + kk + sk);
            __syncthreads();
            {
                const int wc0 = sc ^ sk;
                const int wc1 = (sc + 32) ^ sk;
                As[sk + 0][wc0] = a0.x; As[sk + 1][wc0] = a0.y;
                As[sk + 2][wc0] = a0.z; As[sk + 3][wc0] = a0.w;
                As[sk + 0][wc1] = a1.x; As[sk + 1][wc1] = a1.y;
                As[sk + 2][wc1] = a1.z; As[sk + 3][wc1] = a1.w;
                Bsh[sk + 0][wc0] = b0.x; Bsh[sk + 1][wc0] = b0.y;
                Bsh[sk + 2][wc0] = b0.z; Bsh[sk + 3][wc0] = b0.w;
                Bsh[sk + 0][wc1] = b1.x; Bsh[sk + 1][wc1] = b1.y;
                Bsh[sk + 2][wc1] = b1.z; Bsh[sk + 3][wc1] = b1.w;
            }
            __syncthreads();
            float acc[4][4];
#pragma unroll
            for (int r = 0; r < 4; ++r)
#pragma unroll
                for (int c = 0; c < 4; ++c) acc[r][c] = 0.f;
#pragma unroll
            for (int k = 0; k < 32; ++k) {
                const int rsw = (k >> 2) << 2;
                float4 a = *(const float4*)&As[k][(ty * 4) ^ rsw];
                float4 b = *(const float4*)&Bsh[k][(tx * 4) ^ rsw];
                acc[0][0] = fmaf(a.x, b.x, acc[0][0]);
                acc[0][1] = fmaf(a.x, b.y, acc[0][1]);
                acc[0][2] = fmaf(a.x, b.z, acc[0][2]);
                acc[0][3] = fmaf(a.x, b.w, acc[0][3]);
                acc[1][0] = fmaf(a.y, b.x, acc[1][0]);
                acc[1][1] = fmaf(a.y, b.y, acc[1][1]);
                acc[1][2] = fmaf(a.y, b.z, acc[1][2]);
                acc[1][3] = fmaf(a.y, b.w, acc[1][3]);
                acc[2][0] = fmaf(a.z, b.x, acc[2][0]);
                acc[2][1] = fmaf(a.z, b.y, acc[2][1]);
                acc[2][2] = fmaf(a.z, b.z, acc[2][2]);
                acc[2][3] = fmaf(a.z, b.w, acc[2][3]);
                acc[3][0] = fmaf(a.w, b.x, acc[3][0]);
                acc[3][1] = fmaf(a.w, b.y, acc[3][1]);
                acc[3][2] = fmaf(a.w, b.z, acc[3][2]);
                acc[3][3] = fmaf(a.w, b.w, acc[3][3]);
            }
#pragma unroll
            for (int r = 0; r < 4; ++r)
#pragma unroll
                for (int c = 0; c < 4; ++c) acc64[r][c] += (double)acc[r][c];
        }
        const int cbase = c0 + tx * 4;
        double nna[4];
#pragma unroll
        for (int c = 0; c < 4; ++c) nna[c] = n2[cbase + c];
#pragma unroll
        for (int r = 0; r < 4; ++r) {
#pragma unroll
            for (int c = 0; c < 4; ++c) {
                const double s = nna[c] - 2.0 * acc64[r][c];
                const int j = cbase + c;
                if (s < v0[r]) { v1[r] = v0[r]; v0[r] = s; i0[r] = j; }
                else if (s < v1[r]) { v1[r] = s; }
            }
        }
    }
#pragma unroll
    for (int r = 0; r < 4; ++r) {
        double a0 = v0[r], a1 = v1[r];
        int    ai = i0[r];
#pragma unroll
        for (int m = 1; m <= 8; m <<= 1) {
            double b0 = __shfl_xor(a0, m);
            double b1 = __shfl_xor(a1, m);
            int    bi = __shfl_xor(ai, m);
            bool take = (b0 < a0) || (b0 == a0 && bi < ai);
            if (take) { a1 = fmin(a0, b1); a0 = b0; ai = bi; }
            else      { a1 = fmin(a1, b0); }
        }
        if (tx == 0) {
            const int row = row0 + ty * 4 + r;
            pv0[sp * NROWS + row] = a0;
            pv1[sp * NROWS + row] = a1;
            pi0[sp * NROWS + row] = ai;
        }
    }
}

__global__ __launch_bounds__(256) void dmfb_finalize(const double* __restrict__ n1,
                                                     const double* __restrict__ pv0,
                                                     const double* __restrict__ pv1,
                                                     const int* __restrict__ pi0,
                                                     float* __restrict__ out) {
    const int i = blockIdx.x * blockDim.x + threadIdx.x;
    if (i >= NROWS) return;
    double a0 = pv0[i], a1 = pv1[i];
    int    ai = pi0[i];
#pragma unroll
    for (int h = 1; h < 4; ++h) {
        const double b0 = pv0[h * NROWS + i];
        const double b1 = pv1[h * NROWS + i];
        const int    bi = pi0[h * NROWS + i];
        bool take = (b0 < a0) || (b0 == a0 && bi < ai);
        if (take) { a1 = fmin(a0, b1); a0 = b0; ai = bi; }
        else      { a1 = fmin(a1, b0); }
    }
    const double nn = n1[i];
    const double d0  = sqrt(fmax(nn + a0, 0.0));
    const double d1v = sqrt(fmax(nn + a1, 0.0));
    const float ratio = (float)(d0 / d1v);
    const bool mask = (ratio <= 0.8f);
    out[i] = mask ? ratio : 0.f;
    out[NROWS + 2 * i]     = (float)i;
    out[NROWS + 2 * i + 1] = (float)ai;
    out[3 * NROWS + i] = mask ? 1.f : 0.f;
}

extern "C" void kernel_launch(void* const* d_in, const int* in_sizes, int n_in,
                              void* d_out, int out_size, void* d_ws, size_t ws_size,
                              hipStream_t stream) {
    const float* d1 = (const float*)d_in[0];
    const float* d2 = (const float*)d_in[1];
    float* out = (float*)d_out;

    const size_t ELEMS = (size_t)NROWS * DIM;              // 4,194,304
    const size_t need = 4 * ELEMS * 2 + NROWS * 4          // hi/lo arrays + n2
                      + (size_t)NROWS * NSPLIT * 16;       // partials
    if (ws_size >= need) {
        unsigned short* Ahi = (unsigned short*)d_ws;
        unsigned short* Alo = Ahi + ELEMS;
        unsigned short* Bhi = Alo + ELEMS;
        unsigned short* Blo = Bhi + ELEMS;
        float* n2 = (float*)(Blo + ELEMS);
        float4* part = (float4*)(n2 + NROWS);

        dm_split<<<(2 * ELEMS) / (256 * 8), 256, 0, stream>>>(d1, d2, Ahi, Alo, Bhi, Blo);
        dm_norms2<<<NROWS / 4, 256, 0, stream>>>(d2, n2);
        dm_match_mfma<<<(NROWS / 256) * NSPLIT, 256, 0, stream>>>(Ahi, Alo, Bhi, Blo, n2, part);
        dm_rescore<<<NROWS, 256, 0, stream>>>(d1, d2, part, out);
    } else {
        double* n1  = (double*)d_ws;
        double* n2  = n1 + NROWS;
        double* pv0 = n2 + NROWS;
        double* pv1 = pv0 + 4 * NROWS;
        int*    pi0 = (int*)(pv1 + 4 * NROWS);
        dmfb_norms<<<(2 * NROWS) / 4, 256, 0, stream>>>(d1, d2, n1, n2);
        dmfb_match<<<(NROWS / 64) * 4, 256, 0, stream>>>(d1, d2, n2, pv0, pv1, pi0);
        dmfb_finalize<<<NROWS / 256, 256, 0, stream>>>(n1, pv0, pv1, pi0, out);
    }
}